// Round 2
// baseline (4091.640 us; speedup 1.0000x reference)
//
#include <hip/hip_runtime.h>

// R12: R10 structure + the two CORRECT pieces of R11.
//  - Masked ah reads: epilogue consumes only C rows {0,4,8,12} (lane reads
//    its reg0 = row 4q). A-frag row = lane&15, so only lanes (lane&3)==0
//    need valid h data. Wrap the 8 ds_read_b128 in if((tid&3)==0):
//    delivered bytes/instr 1KB -> 256B. Inactive lanes keep zero ah ->
//    garbage only lands in never-read C rows; MFMA runs at full exec.
//  - Weights/bias/proj prescaled by 2*log2(e): MFMA yields z''=2log2e*z,
//    so e^{2z} = v_exp_f32(z'') directly (drops 2 serial v_mul from tail).
//  - REVERTED R11's tile-permuted B-frags: a B-fragment's k-rows live
//    across q lane-groups, so per-q tile permutation mixes tiles along K
//    inside one MFMA (the R11 absmax=1.23 bug). Tail is R10's
//    sel4-over-slots (12 cndmask + 3 adds).
// 64 WGs (1/CU) x 256 thr (4 waves). Wave g owns cols [64g,64g+64);
// lane (n=lane&15,q=lane>>4) owns col 64g+16q+n at the epilogue.

typedef _Float16 half8 __attribute__((ext_vector_type(8)));
typedef _Float16 half4 __attribute__((ext_vector_type(4)));
typedef float    f32x4 __attribute__((ext_vector_type(4)));

#define LGKM_BARRIER() asm volatile("s_waitcnt lgkmcnt(0)\n\ts_barrier" ::: "memory")

__device__ __forceinline__ half8 cvt8s(float4 v0, float4 v1, float s) {
    half8 hv;
    hv[0]=(_Float16)(v0.x*s); hv[1]=(_Float16)(v0.y*s);
    hv[2]=(_Float16)(v0.z*s); hv[3]=(_Float16)(v0.w*s);
    hv[4]=(_Float16)(v1.x*s); hv[5]=(_Float16)(v1.y*s);
    hv[6]=(_Float16)(v1.z*s); hv[7]=(_Float16)(v1.w*s);
    return hv;
}
__device__ __forceinline__ half4 cvt4(float4 v) {
    half4 hv;
    hv[0]=(_Float16)v.x; hv[1]=(_Float16)v.y;
    hv[2]=(_Float16)v.z; hv[3]=(_Float16)v.w;
    return hv;
}

// select a[q][0] without dynamic indexing (3 cndmask)
__device__ __forceinline__ float sel4(const f32x4 (&a)[4], int q) {
    float v0 = (q & 2) ? a[2][0] : a[0][0];
    float v1 = (q & 2) ? a[3][0] : a[1][0];
    return (q & 1) ? v1 : v0;
}

__global__ void __launch_bounds__(256, 1)
ltc_fused(const float* __restrict__ x,      // [B,T,128]
          const float* __restrict__ W_in,   // [256,128]
          const float* __restrict__ b_in,   // [256]
          const float* __restrict__ W_rec,  // [256,256]
          const float* __restrict__ b_rec,  // [256]
          const float* __restrict__ tau,    // [256]
          const int*   __restrict__ num_layers,
          float*       __restrict__ out,    // [B,256]
          int T)
{
    const int b    = blockIdx.x;
    const int tid  = threadIdx.x;
    const int lane = tid & 63;
    const int g    = tid >> 6;             // wave: out-cols [64g, 64g+64)
    const int n    = lane & 15;
    const int q    = lane >> 4;
    const int L    = num_layers[0];
    const int mycol = 64*g + 16*q + n;     // this lane's epilogue column

    __shared__ _Float16 hbuf[2][256];           // h, PLAIN layout, dbuf
    __shared__ _Float16 xstage[2][16][16][8];   // x chunk, A-frag order
    __shared__ _Float16 pchunk[32][4][16][4];   // proj chunk [ts][g][n][t4]

    // ---- stationary B-frags: W_rec (4x8) + W_in (4x4), f16, prescaled ----
    const float PRE = 2.8853900817779268f;      // 2*log2(e)
    half8 bh[4][8];
    half8 bx[4][4];
    float biasv[4];
#pragma unroll
    for (int t4 = 0; t4 < 4; ++t4) {
        const int col = 64*g + 16*t4 + n;
        const float* rp = &W_rec[col * 256 + 8*q];
#pragma unroll
        for (int i = 0; i < 8; ++i)
            bh[t4][i] = cvt8s(*(const float4*)&rp[32*i],
                              *(const float4*)&rp[32*i + 4], PRE);
        const float* ip = &W_in[col * 128 + 8*q];
#pragma unroll
        for (int i = 0; i < 4; ++i)
            bx[t4][i] = cvt8s(*(const float4*)&ip[32*i],
                              *(const float4*)&ip[32*i + 4], PRE);
        biasv[t4] = (b_in[col] + b_rec[col]) * PRE;
    }
    const float sj   = 0.1f / fminf(fmaxf(tau[mycol], 0.1f), 5.0f);
    const float nsj2 = -2.0f * sj;
    float hj = 0.0f;

    hbuf[0][tid] = (_Float16)0.0f;         // zero h buffer 0 (256 thr)

    const float* xb  = x + (size_t)b * T * 128;
    const int    t_u = tid >> 3;           // staging: timestep in chunk
    const int    c8  = tid & 7;            // staging: 16-f32 block index
    const int    Mts = t_u >> 4, ms = t_u & 15;

    // ---- chunk-0 prefetch into registers ----
    float4 xpre0, xpre1, xpre2, xpre3;
    {
        int tg = t_u; if (tg > T - 1) tg = T - 1;
        const float4* src = (const float4*)(xb + (size_t)tg * 128 + 16*c8);
        xpre0 = src[0]; xpre1 = src[1]; xpre2 = src[2]; xpre3 = src[3];
    }

    // persistent A-frags: zero-init so masked-off lanes never hold NaN
    half8 ah[8] = {};

    int hb = 0;
    for (int tc = 0; tc < T; tc += 32) {
        // ---- stage chunk from regs (vmcnt wait folds in here) ----
        *(half4*)&xstage[Mts][2*c8    ][ms][0] = cvt4(xpre0);
        *(half4*)&xstage[Mts][2*c8    ][ms][4] = cvt4(xpre1);
        *(half4*)&xstage[Mts][2*c8 + 1][ms][0] = cvt4(xpre2);
        *(half4*)&xstage[Mts][2*c8 + 1][ms][4] = cvt4(xpre3);
        __syncthreads();

        // ---- project chunk: proj = (x·W_in^T + b_in + b_rec) * PRE ----
#pragma unroll
        for (int Mt = 0; Mt < 2; ++Mt) {
            half8 ax[4];
#pragma unroll
            for (int ks = 0; ks < 4; ++ks)
                ax[ks] = *(const half8*)&xstage[Mt][4*ks + q][n][0];
            f32x4 pa[4];
#pragma unroll
            for (int t4 = 0; t4 < 4; ++t4)
                pa[t4] = (f32x4){biasv[t4], biasv[t4], biasv[t4], biasv[t4]};
#pragma unroll
            for (int ks = 0; ks < 4; ++ks)
#pragma unroll
                for (int t4 = 0; t4 < 4; ++t4)
                    pa[t4] = __builtin_amdgcn_mfma_f32_16x16x32_f16(
                        ax[ks], bx[t4][ks], pa[t4], 0, 0, 0);
#pragma unroll
            for (int r = 0; r < 4; ++r) {
                half4 pk;
                pk[0] = (_Float16)pa[0][r]; pk[1] = (_Float16)pa[1][r];
                pk[2] = (_Float16)pa[2][r]; pk[3] = (_Float16)pa[3][r];
                *(half4*)&pchunk[16*Mt + 4*q + r][g][n][0] = pk;
            }
        }
        __syncthreads();

        // ---- issue next chunk's global loads; fly across lgkm barriers ----
        {
            const int nc = (tc + 32 < T) ? tc + 32 : tc;
            int tg = nc + t_u; if (tg > T - 1) tg = T - 1;
            const float4* src = (const float4*)(xb + (size_t)tg * 128 + 16*c8);
            xpre0 = src[0]; xpre1 = src[1]; xpre2 = src[2]; xpre3 = src[3];
        }

        // ---- steady scan: LDS-only, lgkm-barriers only ----
        const int tlen = (T - tc < 32) ? (T - tc) : 32;
        half4 xv_cur = *(const half4*)&pchunk[0][g][n][0];   // ts=0 xc
        for (int ts = 0; ts < tlen; ++ts) {
            float xc[4];
#pragma unroll
            for (int t4 = 0; t4 < 4; ++t4) xc[t4] = (float)xv_cur[t4];
            half4 xv_nxt = xv_cur;

            for (int l = 0; l < L; ++l) {
                // only A-rows {0,4,8,12} are consumed (C reg0 = row 4q):
                // mask the broadcast reads to those 16 lanes.
                if ((tid & 3) == 0) {
#pragma unroll
                    for (int i = 0; i < 8; ++i)
                        ah[i] = *(const half8*)&hbuf[hb][32*i + 8*q];
                }
                if (l == 0) {
                    const int tsn = (ts + 1 < tlen) ? ts + 1 : ts;
                    xv_nxt = *(const half4*)&pchunk[tsn][g][n][0];
                }

                // term1 = h + s*(1-h): off critical path (needs only hj)
                const float term1 = __builtin_fmaf(sj, 1.0f - hj, hj);

                f32x4 A0[4], A1[4], A2[4], A3[4];
#pragma unroll
                for (int t4 = 0; t4 < 4; ++t4) {
                    A0[t4] = (f32x4){xc[t4], xc[t4], xc[t4], xc[t4]};
                    A1[t4] = (f32x4){0.f, 0.f, 0.f, 0.f};
                    A2[t4] = (f32x4){0.f, 0.f, 0.f, 0.f};
                    A3[t4] = (f32x4){0.f, 0.f, 0.f, 0.f};
                }
#pragma unroll
                for (int t4 = 0; t4 < 4; ++t4) {
                    A0[t4] = __builtin_amdgcn_mfma_f32_16x16x32_f16(
                        ah[0], bh[t4][0], A0[t4], 0, 0, 0);
                    A1[t4] = __builtin_amdgcn_mfma_f32_16x16x32_f16(
                        ah[2], bh[t4][2], A1[t4], 0, 0, 0);
                    A2[t4] = __builtin_amdgcn_mfma_f32_16x16x32_f16(
                        ah[4], bh[t4][4], A2[t4], 0, 0, 0);
                    A3[t4] = __builtin_amdgcn_mfma_f32_16x16x32_f16(
                        ah[6], bh[t4][6], A3[t4], 0, 0, 0);
                }
#pragma unroll
                for (int t4 = 0; t4 < 4; ++t4) {
                    A0[t4] = __builtin_amdgcn_mfma_f32_16x16x32_f16(
                        ah[1], bh[t4][1], A0[t4], 0, 0, 0);
                    A1[t4] = __builtin_amdgcn_mfma_f32_16x16x32_f16(
                        ah[3], bh[t4][3], A1[t4], 0, 0, 0);
                    A2[t4] = __builtin_amdgcn_mfma_f32_16x16x32_f16(
                        ah[5], bh[t4][5], A2[t4], 0, 0, 0);
                    A3[t4] = __builtin_amdgcn_mfma_f32_16x16x32_f16(
                        ah[7], bh[t4][7], A3[t4], 0, 0, 0);
                }

                // tail: select this lane's tile (slot q), reg0 = row 4q
                float z = (sel4(A0, q) + sel4(A1, q))
                        + (sel4(A2, q) + sel4(A3, q));
                float e;   // e = e^{2*z_true} = 2^{z''} (prescaled weights)
                asm("v_exp_f32 %0, %1\n\ts_nop 0" : "=v"(e) : "v"(z));
                float r = __builtin_amdgcn_rcpf(e + 1.0f);      // 1/(e+1)
                hj = __builtin_fmaf(nsj2, r, term1);            // h+s*(tanh-h)
                hbuf[hb ^ 1][mycol] = (_Float16)hj;
                LGKM_BARRIER();
                hb ^= 1;
            }
            xv_cur = xv_nxt;
        }
    }

    out[(size_t)b * 256 + mycol] = hj;
}

extern "C" void kernel_launch(void* const* d_in, const int* in_sizes, int n_in,
                              void* d_out, int out_size, void* d_ws, size_t ws_size,
                              hipStream_t stream) {
    const float* x     = (const float*)d_in[0];
    const float* W_in  = (const float*)d_in[1];
    const float* b_in  = (const float*)d_in[2];
    const float* W_rec = (const float*)d_in[3];
    const float* b_rec = (const float*)d_in[4];
    const float* tau   = (const float*)d_in[5];
    const int*   numl  = (const int*)d_in[6];

    const int H = in_sizes[2];            // 256
    const int I = in_sizes[1] / H;        // 128
    const int B = out_size / H;           // 64
    const int T = in_sizes[0] / (B * I);  // 4096

    ltc_fused<<<B, 256, 0, stream>>>(x, W_in, b_in, W_rec, b_rec, tau,
                                     numl, (float*)d_out, T);
}